// Round 9
// baseline (2907.920 us; speedup 1.0000x reference)
//
#include <hip/hip_runtime.h>

#define NN 1024
#define NOPEN 128
#define NHID 256
#define NSTART 40
#define NCLOSE 3
#define NLAYERS 40
#define KSZ 9

static constexpr float H2 = 0.01f;     // h*h, h = 0.1
static constexpr float IN_EPS = 1e-5f; // instance norm eps

using floatx4 = __attribute__((ext_vector_type(4))) float;
using bfrag = __attribute__((ext_vector_type(8))) short; // 8 bf16 = 4 VGPRs

__device__ __forceinline__ ushort f2bf(float f) {
    union { float f; unsigned u; } v; v.f = f;
    unsigned r = v.u + 0x7fffu + ((v.u >> 16) & 1u); // RNE
    return (ushort)(r >> 16);
}

// weight prep in MFMA-fragment-major order (Wf1: conv A-frags, Wf2: convT A-frags)
__device__ __forceinline__ void prepw_piece(const float* __restrict__ W, ushort* __restrict__ Wf1,
                                            ushort* __restrict__ Wf2, int lb, int lsrc, int tid) {
    if (lb < 72) {
        int z = lb / 36, rem = lb % 36;
        int t = rem >> 2, q = rem & 3;
        const float* Wz = W + (size_t)(lsrc * 2 + z) * (NHID * NOPEN * KSZ);
        ushort* dst = Wf1 + (((size_t)(z * 9 + t) * 64 + q * 16) << 9);
#pragma unroll
        for (int r = 0; r < 32; ++r) {
            int ei = r * 256 + tid;
            int g = q * 4 + (ei >> 11);
            int kc = (ei >> 9) & 3;
            int lm = (ei >> 3) & 15, lq = (ei >> 7) & 3;
            int e = ei & 7;
            int co = g * 16 + lm, ci = kc * 32 + lq * 8 + e;
            dst[ei] = f2bf(Wz[co * (NOPEN * KSZ) + ci * KSZ + t]);
        }
    } else {
        int p2 = lb - 72;
        int z = p2 / 36, rem = p2 % 36;
        int t = rem >> 2, q = rem & 3;
        const float* Wz = W + (size_t)(lsrc * 2 + z) * (NHID * NOPEN * KSZ);
        ushort* dst = Wf2 + (((size_t)(z * 9 + t) * 64 + q * 16) << 9);
#pragma unroll
        for (int r = 0; r < 32; ++r) {
            int ei = r * 256 + tid;
            int fb = q * 16 + (ei >> 9);
            int g = fb >> 3, j = fb & 7;
            int lm = (ei >> 3) & 15, lq = (ei >> 7) & 3;
            int e = ei & 7;
            int ci = g * 16 + lm, co = j * 32 + lq * 8 + e;
            dst[ei] = f2bf(Wz[co * (NOPEN * KSZ) + ci * KSZ + t]);
        }
    }
}

// ---------------- opening: Zc/Zold/Zct(layer0) + weight prep(layer0, slot0) + pads + sig/cnt=0 ----------------
__global__ __launch_bounds__(256) void k_open(const float* __restrict__ Kopen, const float* __restrict__ Z,
                       float* __restrict__ Zc, float* __restrict__ Zold,
                       const float* __restrict__ Bias0, ushort* __restrict__ Zct,
                       ushort* __restrict__ At0, ushort* __restrict__ At1,
                       const float* __restrict__ W, ushort* __restrict__ Wf1,
                       ushort* __restrict__ Wf2, float* __restrict__ sig,
                       int* __restrict__ cnt) {
    const int v = blockIdx.x, tid = threadIdx.x;
    if (v < 512) {
        int o = v >> 2, n = (v & 3) * 256 + tid;
        float acc = 0.f;
#pragma unroll
        for (int s = 0; s < NSTART; ++s)
            acc = fmaf(Kopen[o * NSTART + s], Z[s * NN + n], acc);
        Zc[o * NN + n] = acc;
        Zold[o * NN + n] = acc;
#pragma unroll
        for (int z = 0; z < 2; ++z)
            Zct[z * (1032 * 128) + (n + 4) * 128 + o] = f2bf(acc + Bias0[z * NOPEN + o]);
    } else if (v < 656) {
        prepw_piece(W, Wf1, Wf2, v - 512, 0, tid);
    } else {
        if (tid == 0) sig[0] = 0.f;
        if (tid < 32) cnt[tid] = 0;
        for (int idx = tid; idx < 1024; idx += 256) {
            int z = idx >> 9, rr = idx & 511;
            ushort* Zz = Zct + z * (1032 * 128);
            Zz[rr] = 0; Zz[1028 * 128 + rr] = 0;
        }
        for (int idx = tid; idx < 2048; idx += 256) {
            int a = idx >> 10, rr = idx & 1023;
            ushort* A = a ? At1 : At0;
            A[rr] = 0; A[1028 * 256 + rr] = 0;
        }
    }
}

// ---------------- D2 = max(sq_i + sq_j - 2 Z^T Z, 0); sum(D2) -> sig ----------------
__global__ __launch_bounds__(256) void k_d2(const float* __restrict__ Zc,
                                            float* __restrict__ D2, float* __restrict__ sig) {
    __shared__ __align__(16) float Zi[32 * 36];
    __shared__ __align__(16) float Zj[32 * 68];
    __shared__ float sqi[32], sqj[64];
    __shared__ float red[4];
    const int tid = threadIdx.x;
    const int tx = tid & 15, ty = tid >> 4;
    const int j0 = blockIdx.x * 64, i0 = blockIdx.y * 32;
    if (tid < 32) sqi[tid] = 0.f;
    else if (tid < 96) sqj[tid - 32] = 0.f;
    float acc[2][4] = {};
    for (int c0 = 0; c0 < NOPEN; c0 += 32) {
        for (int idx = tid; idx < 32 * 32; idx += 256) {
            int c = idx >> 5, ii = idx & 31;
            Zi[c * 36 + ii] = Zc[(c0 + c) * NN + i0 + ii];
        }
        for (int idx = tid; idx < 32 * 64; idx += 256) {
            int c = idx >> 6, jj = idx & 63;
            Zj[c * 68 + jj] = Zc[(c0 + c) * NN + j0 + jj];
        }
        __syncthreads();
        if (tid < 32) {
            float s = 0.f;
            for (int c = 0; c < 32; ++c) { float x = Zi[c * 36 + tid]; s = fmaf(x, x, s); }
            sqi[tid] += s;
        } else if (tid < 96) {
            int jj = tid - 32;
            float s = 0.f;
            for (int c = 0; c < 32; ++c) { float x = Zj[c * 68 + jj]; s = fmaf(x, x, s); }
            sqj[jj] += s;
        }
#pragma unroll 8
        for (int c = 0; c < 32; ++c) {
            float2 zi = *(const float2*)&Zi[c * 36 + ty * 2];
            float4 zj = *(const float4*)&Zj[c * 68 + tx * 4];
            acc[0][0] = fmaf(zi.x, zj.x, acc[0][0]);
            acc[0][1] = fmaf(zi.x, zj.y, acc[0][1]);
            acc[0][2] = fmaf(zi.x, zj.z, acc[0][2]);
            acc[0][3] = fmaf(zi.x, zj.w, acc[0][3]);
            acc[1][0] = fmaf(zi.y, zj.x, acc[1][0]);
            acc[1][1] = fmaf(zi.y, zj.y, acc[1][1]);
            acc[1][2] = fmaf(zi.y, zj.z, acc[1][2]);
            acc[1][3] = fmaf(zi.y, zj.w, acc[1][3]);
        }
        __syncthreads();
    }
    float part = 0.f;
#pragma unroll
    for (int m = 0; m < 2; ++m) {
        int i = i0 + ty * 2 + m;
        float sqi_v = sqi[ty * 2 + m];
        float4 d;
        d.x = fmaxf(sqi_v + sqj[tx * 4 + 0] - 2.f * acc[m][0], 0.f);
        d.y = fmaxf(sqi_v + sqj[tx * 4 + 1] - 2.f * acc[m][1], 0.f);
        d.z = fmaxf(sqi_v + sqj[tx * 4 + 2] - 2.f * acc[m][2], 0.f);
        d.w = fmaxf(sqi_v + sqj[tx * 4 + 3] - 2.f * acc[m][3], 0.f);
        *(float4*)&D2[(size_t)i * NN + j0 + tx * 4] = d;
        part += (d.x + d.y) + (d.z + d.w);
    }
#pragma unroll
    for (int off = 32; off > 0; off >>= 1) part += __shfl_down(part, off);
    if ((tid & 63) == 0) red[tid >> 6] = part;
    __syncthreads();
    if (tid == 0) atomicAdd(sig, red[0] + red[1] + red[2] + red[3]);
}

// ---------------- deg_i = sum_j exp(-D2_ij/sigma); Dh_i = rsqrt(deg_i) ----------------
__global__ void k_deg(const float* __restrict__ D2, const float* __restrict__ sig,
                      float* __restrict__ Dh) {
    __shared__ float red[4];
    int i = blockIdx.x, tid = threadIdx.x;
    float inv = 1.f / (sig[0] * (1.f / 1048576.f) + 1e-12f);
    float4 v = *(const float4*)&D2[(size_t)i * NN + tid * 4];
    float s = __expf(-v.x * inv) + __expf(-v.y * inv) + __expf(-v.z * inv) + __expf(-v.w * inv);
#pragma unroll
    for (int off = 32; off > 0; off >>= 1) s += __shfl_down(s, off);
    if ((tid & 63) == 0) red[tid >> 6] = s;
    __syncthreads();
    if (tid == 0) Dh[i] = rsqrtf(red[0] + red[1] + red[2] + red[3]);
}

// ---------------- Lb_ij = bf16( delta_ij - Dh_i Dh_j exp(-D2_ij/sigma) ) ----------------
__global__ void k_L(const float* __restrict__ D2, const float* __restrict__ sig,
                    const float* __restrict__ Dh, ushort* __restrict__ Lb) {
    int i = blockIdx.x, tid = threadIdx.x;
    int j = tid * 4;
    float inv = 1.f / (sig[0] * (1.f / 1048576.f) + 1e-12f);
    float dhi = Dh[i];
    float4 v = *(const float4*)&D2[(size_t)i * NN + j];
    float4 dj = *(const float4*)&Dh[j];
    float4 o;
    o.x = -dhi * dj.x * __expf(-v.x * inv);
    o.y = -dhi * dj.y * __expf(-v.y * inv);
    o.z = -dhi * dj.z * __expf(-v.z * inv);
    o.w = -dhi * dj.w * __expf(-v.w * inv);
    if (i == j + 0) o.x += 1.f;
    if (i == j + 1) o.y += 1.f;
    if (i == j + 2) o.z += 1.f;
    if (i == j + 3) o.w += 1.f;
    ushort4 ob; ob.x = f2bf(o.x); ob.y = f2bf(o.y); ob.z = f2bf(o.z); ob.w = f2bf(o.w);
    *(ushort4*)&Lb[(size_t)i * NN + j] = ob;
}

// ---------------- MFMA conv1d + next-layer weight prep: grid 656 flattened ----------------
__global__ __launch_bounds__(256) void k_convprep(const ushort* __restrict__ Zct,
        const ushort* __restrict__ Wf1, float* __restrict__ C0, ushort* __restrict__ C1b,
        const float* __restrict__ W, ushort* __restrict__ Wf1n, ushort* __restrict__ Wf2n,
        int lnext, int doprep) {
    const int b = blockIdx.x, tid = threadIdx.x;
    if (b >= 512) {
        if (doprep) prepw_piece(W, Wf1n, Wf2n, b - 512, lnext, tid);
        return;
    }
    const int xb = b & 31, yb = (b >> 5) & 7, z = b >> 8;
    const int p0 = xb * 32, co0 = yb * 32;
    __shared__ ushort Xs[40 * 136];
    const ushort* Zz = Zct + z * (1032 * 128);
    for (int idx = tid; idx < 640; idx += 256) {
        int row = idx >> 4, ch = (idx & 15) * 8;
        *(bfrag*)&Xs[row * 136 + ch] = *(const bfrag*)&Zz[(p0 + row) * 128 + ch];
    }
    __syncthreads();
    const int l = tid & 63, wv = tid >> 6;
    const int wm = wv >> 1, wn = wv & 1;
    const int lm = l & 15, lq = l >> 4;
    const ushort* wf = Wf1 + (((size_t)z * 144 + (yb * 2 + wm)) << 11) + l * 8;
    floatx4 acc = {};
    bfrag a_cur[4];
#pragma unroll
    for (int kc = 0; kc < 4; ++kc) a_cur[kc] = *(const bfrag*)(wf + (kc << 9));
    for (int t = 0; t < 9; ++t) {
        bfrag a_nxt[4];
        if (t < 8) {
            const ushort* wptr = wf + (size_t)(t + 1) * (16 << 11);
#pragma unroll
            for (int kc = 0; kc < 4; ++kc) a_nxt[kc] = *(const bfrag*)(wptr + (kc << 9));
        }
        const int xbase = (wn * 16 + lm + t) * 136 + lq * 8;
#pragma unroll
        for (int kc = 0; kc < 4; ++kc) {
            bfrag b0 = *(const bfrag*)&Xs[xbase + kc * 32];
            acc = __builtin_amdgcn_mfma_f32_16x16x32_bf16(a_cur[kc], b0, acc, 0, 0, 0);
        }
#pragma unroll
        for (int kc = 0; kc < 4; ++kc) a_cur[kc] = a_nxt[kc];
    }
    const int cog = co0 + wm * 16 + lq * 4;
    const int pg = p0 + wn * 16 + lm;
#pragma unroll
    for (int r = 0; r < 4; ++r) {
        if (z == 0) C0[(cog + r) * NN + pg] = acc[r];
        else        C1b[(cog + r) * NN + pg] = f2bf(acc[r]);
    }
}

// ---------------- XL1 split-K, DETERMINISTIC slot writes: P1[k][m][n] = C1b[:,kc:]@L[kc:,:] slice ----------------
// grid (16 nt of 64, 4 mt of 64, 8 k). Plain stores; no atomics, no pre-zero. Summed in k_inorm (R0 order).
__global__ __launch_bounds__(256) void k_xl1(const ushort* __restrict__ X,
                                             const ushort* __restrict__ Lb,
                                             float* __restrict__ P1) {
    __shared__ __align__(16) ushort As[64 * 136];
    __shared__ __align__(16) ushort Bs[64 * 136];
    const int tid = threadIdx.x;
    const int lane = tid & 63, wave = tid >> 6;
    const int wm = wave >> 1, wn = wave & 1;
    const int n0 = blockIdx.x * 64, m0 = blockIdx.y * 64, kc = blockIdx.z * 128;
    {
        int q = tid;
#pragma unroll
        for (int r = 0; r < 4; ++r, q += 256) {
            int row = q >> 4, ch = (q & 15) * 8;
            *(bfrag*)&As[row * 136 + ch] = *(const bfrag*)&X[(m0 + row) * NN + kc + ch];
        }
        q = tid;
#pragma unroll
        for (int r = 0; r < 4; ++r, q += 256) {
            int row = q >> 4, ch = (q & 15) * 8;
            *(bfrag*)&Bs[row * 136 + ch] = *(const bfrag*)&Lb[(n0 + row) * NN + kc + ch];
        }
    }
    __syncthreads();
    floatx4 acc[2][2] = {};
    const int lrow = (lane & 15) * 136;
    const int koff = (lane >> 4) * 8;
#pragma unroll
    for (int ks = 0; ks < 4; ++ks) {
        bfrag a[2], b[2];
#pragma unroll
        for (int i = 0; i < 2; ++i)
            a[i] = *(const bfrag*)&As[(wm * 32 + i * 16) * 136 + lrow + ks * 32 + koff];
#pragma unroll
        for (int j = 0; j < 2; ++j)
            b[j] = *(const bfrag*)&Bs[(wn * 32 + j * 16) * 136 + lrow + ks * 32 + koff];
#pragma unroll
        for (int i = 0; i < 2; ++i)
#pragma unroll
            for (int j = 0; j < 2; ++j)
                acc[i][j] = __builtin_amdgcn_mfma_f32_16x16x32_bf16(a[i], b[j], acc[i][j], 0, 0, 0);
    }
    const int mg0 = m0 + wm * 32 + (lane >> 4) * 4;
    const int ng0 = n0 + wn * 32 + (lane & 15);
#pragma unroll
    for (int i = 0; i < 2; ++i)
#pragma unroll
        for (int j = 0; j < 2; ++j)
#pragma unroll
            for (int r = 0; r < 4; ++r)
                P1[((size_t)blockIdx.z * NHID + (mg0 + i * 16 + r)) * NN + ng0 + j * 16] = acc[i][j][r];
}

// ---------------- instance norm stats; arr=1 sums P1 slots ascending (R0 order) -> A1 ----------------
// grid (NHID, 2), one channel per block
__global__ void k_inorm(const float* __restrict__ C0, const float* __restrict__ P1,
                        float* __restrict__ A1, float* __restrict__ Mu, float* __restrict__ Rs) {
    const int c = blockIdx.x, arr = blockIdx.y, tid = threadIdx.x;
    __shared__ float rs[4], rq[4];
    float4 v;
    if (arr == 0) {
        v = *(const float4*)&C0[c * NN + tid * 4];
    } else {
        v.x = v.y = v.z = v.w = 0.f;
#pragma unroll
        for (int s = 0; s < 8; ++s) {
            float4 p = *(const float4*)&P1[(size_t)(s * NHID + c) * NN + tid * 4];
            v.x += p.x; v.y += p.y; v.z += p.z; v.w += p.w;
        }
        *(float4*)&A1[c * NN + tid * 4] = v;
    }
    float s = (v.x + v.y) + (v.z + v.w);
    float q = (v.x * v.x + v.y * v.y) + (v.z * v.z + v.w * v.w);
#pragma unroll
    for (int off = 32; off > 0; off >>= 1) { s += __shfl_down(s, off); q += __shfl_down(q, off); }
    if ((tid & 63) == 0) { rs[tid >> 6] = s; rq[tid >> 6] = q; }
    __syncthreads();
    if (tid == 0) {
        float S = rs[0] + rs[1] + rs[2] + rs[3];
        float Q = rq[0] + rq[1] + rq[2] + rq[3];
        float mean = S * (1.f / NN);
        float var = Q * (1.f / NN) - mean * mean;
        Mu[arr * NHID + c] = mean;
        Rs[arr * NHID + c] = rsqrtf(var + IN_EPS);
    }
}

// ---------------- normalize + relu + bf16 + transpose -> At[pos+4][co] ----------------
// grid (32 p, 4 co64, 2 arr)
__global__ __launch_bounds__(256) void k_normT(const float* __restrict__ C0,
        const float* __restrict__ A1, const float* __restrict__ Mu, const float* __restrict__ Rs,
        ushort* __restrict__ At0, ushort* __restrict__ At1) {
    const int arr = blockIdx.z;
    const int p0 = blockIdx.x * 32, co0 = blockIdx.y * 64;
    const float* in = arr ? A1 : C0;
    ushort* out = arr ? At1 : At0;
    __shared__ ushort Ls[32 * 72];
    const int tid = threadIdx.x;
#pragma unroll
    for (int r = 0; r < 2; ++r) {
        int idx = r * 256 + tid;      // 64 co x 8 p-chunks(4)
        int col = idx >> 3, pq = idx & 7;
        int co = co0 + col;
        float4 v = *(const float4*)&in[(size_t)co * NN + p0 + pq * 4];
        float m = Mu[arr * NHID + co], sc = Rs[arr * NHID + co];
        Ls[(pq * 4 + 0) * 72 + col] = f2bf(fmaxf((v.x - m) * sc, 0.f));
        Ls[(pq * 4 + 1) * 72 + col] = f2bf(fmaxf((v.y - m) * sc, 0.f));
        Ls[(pq * 4 + 2) * 72 + col] = f2bf(fmaxf((v.z - m) * sc, 0.f));
        Ls[(pq * 4 + 3) * 72 + col] = f2bf(fmaxf((v.w - m) * sc, 0.f));
    }
    __syncthreads();
    {
        int row = tid >> 3, ch = (tid & 7) * 8;   // 32 rows x 8 chunks(8)
        *(bfrag*)&out[(size_t)(p0 + row + 4) * 256 + co0 + ch] = *(const bfrag*)&Ls[row * 72 + ch];
    }
}

// ---------------- MFMA convT + sig zero: grid 513 flattened ----------------
__global__ __launch_bounds__(256) void k_convT_sig(const ushort* __restrict__ At0,
        const ushort* __restrict__ At1, const ushort* __restrict__ Wf2,
        float* __restrict__ Tacc, ushort* __restrict__ T1b, float* __restrict__ sig) {
    const int b = blockIdx.x, tid = threadIdx.x;
    if (b >= 512) {
        if (tid == 0) sig[0] = 0.f;
        return;
    }
    const int xb = b & 31, yb = (b >> 5) & 7, z = b >> 8;
    const int p0 = xb * 32, ci0 = yb * 16;
    __shared__ ushort Al[40 * 264];
    __shared__ float Red[2][64][4];
    const ushort* A = z ? At1 : At0;
    for (int idx = tid; idx < 1280; idx += 256) {
        int row = idx >> 5, ch = (idx & 31) * 8;
        *(bfrag*)&Al[row * 264 + ch] = *(const bfrag*)&A[(p0 + row) * 256 + ch];
    }
    __syncthreads();
    const int l = tid & 63, wv = tid >> 6;
    const int ph = wv & 1, kh = wv >> 1;   // p-half, k-half
    const int lm = l & 15, lq = l >> 4;
    const ushort* wbase = Wf2 + (((size_t)z * 72 + yb) << 12) + ((kh * 4) << 9) + l * 8;
    floatx4 acc0 = {}, acc1 = {};
    bfrag a_cur[4];
#pragma unroll
    for (int jj = 0; jj < 4; ++jj) a_cur[jj] = *(const bfrag*)(wbase + (jj << 9));
    for (int t = 0; t < 9; ++t) {
        bfrag a_nxt[4];
        if (t < 8) {
            const ushort* wptr = wbase + (size_t)(t + 1) * (8 << 12);
#pragma unroll
            for (int jj = 0; jj < 4; ++jj) a_nxt[jj] = *(const bfrag*)(wptr + (jj << 9));
        }
        const int abase = (ph * 16 + lm + 8 - t) * 264 + lq * 8;
#pragma unroll
        for (int jj = 0; jj < 4; jj += 2) {
            bfrag b0 = *(const bfrag*)&Al[abase + (kh * 4 + jj) * 32];
            acc0 = __builtin_amdgcn_mfma_f32_16x16x32_bf16(a_cur[jj], b0, acc0, 0, 0, 0);
            bfrag b1 = *(const bfrag*)&Al[abase + (kh * 4 + jj + 1) * 32];
            acc1 = __builtin_amdgcn_mfma_f32_16x16x32_bf16(a_cur[jj + 1], b1, acc1, 0, 0, 0);
        }
#pragma unroll
        for (int jj = 0; jj < 4; ++jj) a_cur[jj] = a_nxt[jj];
    }
    floatx4 acc = acc0 + acc1;
    __syncthreads();
    if (kh == 1) {
#pragma unroll
        for (int r = 0; r < 4; ++r) Red[ph][l][r] = acc[r];
    }
    __syncthreads();
    if (kh == 0) {
#pragma unroll
        for (int r = 0; r < 4; ++r) acc[r] += Red[ph][l][r];
        const int cig = ci0 + lq * 4;
        const int pg = p0 + ph * 16 + lm;
#pragma unroll
        for (int r = 0; r < 4; ++r) {
            if (z == 0) Tacc[(cig + r) * NN + pg] = acc[r];
            else        T1b[(cig + r) * NN + pg] = f2bf(acc[r]);
        }
    }
}

// ---------------- XL2 deterministic slot split-K + counter-gated fused leapfrog ----------------
// grid (16 nt, 2 mt, 8 k). Contributors write partials to P2[k] via atomicExch (coherent-point write,
// proven path). Last arriver per (nt,mt) assembles a = Tacc_seed + slots s=0..7 ASCENDING (fixed
// order = R0's proven summation) reading via atomicAdd(p,0) (proven-coherent read), then leapfrog.
__global__ __launch_bounds__(256) void k_xl2_leap(const ushort* __restrict__ T1b,
        const ushort* __restrict__ Lb, const float* __restrict__ Tacc,
        float* __restrict__ P2, const float* __restrict__ Zc, float* __restrict__ Zo,
        const float* __restrict__ BiasN, ushort* __restrict__ Zct,
        int* __restrict__ cnt) {
    __shared__ __align__(16) ushort As[64 * 136];
    __shared__ __align__(16) ushort Bs[64 * 136];
    __shared__ int is_last;
    const int tid = threadIdx.x;
    const int lane = tid & 63, wave = tid >> 6;
    const int wm = wave >> 1, wn = wave & 1;
    const int n0 = blockIdx.x * 64, m0 = blockIdx.y * 64, kc = blockIdx.z * 128;
    {
        int q = tid;
#pragma unroll
        for (int r = 0; r < 4; ++r, q += 256) {
            int row = q >> 4, ch = (q & 15) * 8;
            *(bfrag*)&As[row * 136 + ch] = *(const bfrag*)&T1b[(m0 + row) * NN + kc + ch];
        }
        q = tid;
#pragma unroll
        for (int r = 0; r < 4; ++r, q += 256) {
            int row = q >> 4, ch = (q & 15) * 8;
            *(bfrag*)&Bs[row * 136 + ch] = *(const bfrag*)&Lb[(n0 + row) * NN + kc + ch];
        }
    }
    __syncthreads();
    floatx4 acc[2][2] = {};
    const int lrow = (lane & 15) * 136;
    const int koff = (lane >> 4) * 8;
#pragma unroll
    for (int ks = 0; ks < 4; ++ks) {
        bfrag a[2], b[2];
#pragma unroll
        for (int i = 0; i < 2; ++i)
            a[i] = *(const bfrag*)&As[(wm * 32 + i * 16) * 136 + lrow + ks * 32 + koff];
#pragma unroll
        for (int j = 0; j < 2; ++j)
            b[j] = *(const bfrag*)&Bs[(wn * 32 + j * 16) * 136 + lrow + ks * 32 + koff];
#pragma unroll
        for (int i = 0; i < 2; ++i)
#pragma unroll
            for (int j = 0; j < 2; ++j)
                acc[i][j] = __builtin_amdgcn_mfma_f32_16x16x32_bf16(a[i], b[j], acc[i][j], 0, 0, 0);
    }
    const int mg0 = m0 + wm * 32 + (lane >> 4) * 4;
    const int ng0 = n0 + wn * 32 + (lane & 15);
#pragma unroll
    for (int i = 0; i < 2; ++i)
#pragma unroll
        for (int j = 0; j < 2; ++j)
#pragma unroll
            for (int r = 0; r < 4; ++r)
                (void)atomicExch(&P2[((size_t)blockIdx.z << 17) +
                                     (size_t)(mg0 + i * 16 + r) * NN + ng0 + j * 16],
                                 acc[i][j][r]);
    // completion: drain writes, then one device-scope counter bump
    __threadfence();
    __syncthreads();
    if (tid == 0) {
        int old = atomicAdd(&cnt[blockIdx.x * 2 + blockIdx.y], 1);
        is_last = (old == 7) ? 1 : 0;
    }
    __syncthreads();
    if (!is_last) return;
    __threadfence();
    const int nq = (tid & 15) * 4;
    const int mb = tid >> 4;
#pragma unroll
    for (int r = 0; r < 4; ++r) {
        int m = m0 + mb * 4 + r;
        int n = n0 + nq;
        size_t off = (size_t)m * NN + n;
        float4 a = *(const float4*)&Tacc[off];  // seed: cross-dispatch plain read (proven)
#pragma unroll
        for (int s = 0; s < 8; ++s) {           // slots ascending — fixed deterministic order
            size_t so = ((size_t)s << 17) + off;
            a.x += atomicAdd(&P2[so + 0], 0.0f);
            a.y += atomicAdd(&P2[so + 1], 0.0f);
            a.z += atomicAdd(&P2[so + 2], 0.0f);
            a.w += atomicAdd(&P2[so + 3], 0.0f);
        }
        float4 zc = *(const float4*)&Zc[off];
        float4 zo = *(const float4*)&Zo[off];
        float4 zn;
        zn.x = 2.f * zc.x - zo.x - H2 * a.x;
        zn.y = 2.f * zc.y - zo.y - H2 * a.y;
        zn.z = 2.f * zc.z - zo.z - H2 * a.z;
        zn.w = 2.f * zc.w - zo.w - H2 * a.w;
        *(float4*)&Zo[off] = zn;
#pragma unroll
        for (int z = 0; z < 2; ++z) {
            float bz = BiasN[z * NOPEN + m];
            ushort* Zz = Zct + z * (1032 * 128);
            Zz[(n + 4) * 128 + m] = f2bf(zn.x + bz);
            Zz[(n + 5) * 128 + m] = f2bf(zn.y + bz);
            Zz[(n + 6) * 128 + m] = f2bf(zn.z + bz);
            Zz[(n + 7) * 128 + m] = f2bf(zn.w + bz);
        }
    }
    if (tid == 0) cnt[blockIdx.x * 2 + blockIdx.y] = 0; // self-reset for next layer
}

// ---------------- closing: out = concat(Kclose @ Zc, Kclose @ Zold) ----------------
__global__ void k_close(const float* __restrict__ Kclose, const float* __restrict__ Zc,
                        const float* __restrict__ Zold, float* __restrict__ out) {
    int n = blockIdx.x * 256 + threadIdx.x;
    int o = blockIdx.y;
    const float* Zb = blockIdx.z ? Zold : Zc;
    float a = 0.f;
#pragma unroll
    for (int c = 0; c < NOPEN; ++c) a = fmaf(Kclose[o * NOPEN + c], Zb[c * NN + n], a);
    out[blockIdx.z * (NCLOSE * NN) + o * NN + n] = a;
}

extern "C" void kernel_launch(void* const* d_in, const int* in_sizes, int n_in,
                              void* d_out, int out_size, void* d_ws, size_t ws_size,
                              hipStream_t stream) {
    const float* Z      = (const float*)d_in[0];
    const float* Kopen  = (const float*)d_in[1];
    const float* Kclose = (const float*)d_in[2];
    const float* W      = (const float*)d_in[3];
    const float* Bias   = (const float*)d_in[4];
    float* out = (float*)d_out;
    float* ws  = (float*)d_ws;

    // workspace layout (float units) — P1/P2 slot buffers restored (R0 layout)
    float* Zb0   = ws + 0;         // 131072
    float* Zb1   = ws + 131072;    // 131072
    float* D2    = ws + 262144;    // 1048576
    float* C0    = ws + 1310720;   // 262144
    float* A1    = ws + 1572864;   // 262144
    float* Tacc  = ws + 1835008;   // 131072
    float* P1    = ws + 1966080;   // 8*256*1024 = 2097152
    float* P2    = ws + 4063232;   // 8*128*1024 = 1048576
    float* Dh    = ws + 5111808;   // 1024
    float* sig   = ws + 5112832;   // 1024
    float* Mu    = ws + 5113856;   // 1024 (512 used)
    float* Rs    = ws + 5114880;   // 512 used
    int*   cnt   = (int*)(ws + 5115392); // 32 ints
    ushort* Lb  = (ushort*)(ws + 5115904); // 1024*1024 us
    ushort* C1b = (ushort*)(ws + 5640192); // 256*1024 us
    ushort* T1b = (ushort*)(ws + 5771264); // 128*1024 us
    ushort* Zct = (ushort*)(ws + 5836800); // 2*1032*128 us
    ushort* At0 = (ushort*)(ws + 5968896); // 1032*256 us
    ushort* At1 = (ushort*)(ws + 6100992); // 1032*256 us
    ushort* Wf1a = (ushort*)(ws + 6233088); // 294912 us (conv frags, slot 0)
    ushort* Wf2a = (ushort*)(ws + 6380544); // 294912 us (convT frags, slot 0)
    ushort* Wf1b = (ushort*)(ws + 6528000); // 294912 us (slot 1)
    ushort* Wf2b = (ushort*)(ws + 6675456); // 294912 us (slot 1), ends 6822912

    ushort* Wf1s[2] = { Wf1a, Wf1b };
    ushort* Wf2s[2] = { Wf2a, Wf2b };

    k_open<<<dim3(657), 256, 0, stream>>>(Kopen, Z, Zb0, Zb1, Bias, Zct, At0, At1,
                                          W, Wf1s[0], Wf2s[0], sig, cnt);

    float* Zc = Zb0;
    float* Zold = Zb1;
    for (int i = 0; i < NLAYERS; ++i) {
        const int cur = i & 1, nxt = cur ^ 1;
        const int lnext = (i + 1 < NLAYERS) ? i + 1 : NLAYERS - 1;
        const int doprep = (i + 1 < NLAYERS) ? 1 : 0;
        if (i % 10 == 0) {
            k_d2<<<dim3(16, 32), 256, 0, stream>>>(Zc, D2, sig);
            k_deg<<<dim3(NN), 256, 0, stream>>>(D2, sig, Dh);
            k_L<<<dim3(NN), 256, 0, stream>>>(D2, sig, Dh, Lb);
        }
        k_convprep<<<dim3(656), 256, 0, stream>>>(Zct, Wf1s[cur], C0, C1b,
                                                  W, Wf1s[nxt], Wf2s[nxt], lnext, doprep);
        k_xl1<<<dim3(16, 4, 8), 256, 0, stream>>>(C1b, Lb, P1);
        k_inorm<<<dim3(NHID, 2), 256, 0, stream>>>(C0, P1, A1, Mu, Rs);
        k_normT<<<dim3(32, 4, 2), 256, 0, stream>>>(C0, A1, Mu, Rs, At0, At1);
        k_convT_sig<<<dim3(513), 256, 0, stream>>>(At0, At1, Wf2s[cur], Tacc, T1b, sig);
        k_xl2_leap<<<dim3(16, 2, 8), 256, 0, stream>>>(T1b, Lb, Tacc, P2, Zc, Zold,
                                                       Bias + (size_t)lnext * 2 * NOPEN, Zct, cnt);
        float* tmp = Zc; Zc = Zold; Zold = tmp;
    }

    k_close<<<dim3(4, NCLOSE, 2), 256, 0, stream>>>(Kclose, Zc, Zold, out);
}

// Round 10
// 1888.930 us; speedup vs baseline: 1.5395x; 1.5395x over previous
//
#include <hip/hip_runtime.h>

#define NN 1024
#define NOPEN 128
#define NHID 256
#define NSTART 40
#define NCLOSE 3
#define NLAYERS 40
#define KSZ 9

static constexpr float H2 = 0.01f;     // h*h, h = 0.1
static constexpr float IN_EPS = 1e-5f; // instance norm eps

using floatx4 = __attribute__((ext_vector_type(4))) float;
using bfrag = __attribute__((ext_vector_type(8))) short; // 8 bf16 = 4 VGPRs

__device__ __forceinline__ ushort f2bf(float f) {
    union { float f; unsigned u; } v; v.f = f;
    unsigned r = v.u + 0x7fffu + ((v.u >> 16) & 1u); // RNE
    return (ushort)(r >> 16);
}

// weight prep in MFMA-fragment-major order (Wf1: conv A-frags, Wf2: convT A-frags)
// each frag = 512 ushorts = 1KB (64 lanes x 16B), one coalesced dwordx4 per wave.
__device__ __forceinline__ void prepw_piece(const float* __restrict__ W, ushort* __restrict__ Wf1,
                                            ushort* __restrict__ Wf2, int lb, int lsrc, int tid) {
    if (lb < 72) {
        int z = lb / 36, rem = lb % 36;
        int t = rem >> 2, q = rem & 3;
        const float* Wz = W + (size_t)(lsrc * 2 + z) * (NHID * NOPEN * KSZ);
        ushort* dst = Wf1 + (((size_t)(z * 9 + t) * 64 + q * 16) << 9);
#pragma unroll
        for (int r = 0; r < 32; ++r) {
            int ei = r * 256 + tid;
            int g = q * 4 + (ei >> 11);
            int kc = (ei >> 9) & 3;
            int lm = (ei >> 3) & 15, lq = (ei >> 7) & 3;
            int e = ei & 7;
            int co = g * 16 + lm, ci = kc * 32 + lq * 8 + e;
            dst[ei] = f2bf(Wz[co * (NOPEN * KSZ) + ci * KSZ + t]);
        }
    } else {
        int p2 = lb - 72;
        int z = p2 / 36, rem = p2 % 36;
        int t = rem >> 2, q = rem & 3;
        const float* Wz = W + (size_t)(lsrc * 2 + z) * (NHID * NOPEN * KSZ);
        ushort* dst = Wf2 + (((size_t)(z * 9 + t) * 64 + q * 16) << 9);
#pragma unroll
        for (int r = 0; r < 32; ++r) {
            int ei = r * 256 + tid;
            int fb = q * 16 + (ei >> 9);
            int g = fb >> 3, j = fb & 7;
            int lm = (ei >> 3) & 15, lq = (ei >> 7) & 3;
            int e = ei & 7;
            int ci = g * 16 + lm, co = j * 32 + lq * 8 + e;
            dst[ei] = f2bf(Wz[co * (NOPEN * KSZ) + ci * KSZ + t]);
        }
    }
}

// ---------------- opening: Zc/Zold/Zct(layer0) + weight prep(layer0, slot0) + pads + sig=0 + A1=0 ----------------
__global__ __launch_bounds__(256) void k_open(const float* __restrict__ Kopen, const float* __restrict__ Z,
                       float* __restrict__ Zc, float* __restrict__ Zold,
                       const float* __restrict__ Bias0, ushort* __restrict__ Zct,
                       ushort* __restrict__ At0, ushort* __restrict__ At1,
                       const float* __restrict__ W, ushort* __restrict__ Wf1,
                       ushort* __restrict__ Wf2, float* __restrict__ sig, float* __restrict__ A1) {
    const int v = blockIdx.x, tid = threadIdx.x;
    if (v < 512) {
        int o = v >> 2, n = (v & 3) * 256 + tid;
        float acc = 0.f;
#pragma unroll
        for (int s = 0; s < NSTART; ++s)
            acc = fmaf(Kopen[o * NSTART + s], Z[s * NN + n], acc);
        Zc[o * NN + n] = acc;
        Zold[o * NN + n] = acc;
#pragma unroll
        for (int z = 0; z < 2; ++z)
            Zct[z * (1032 * 128) + (n + 4) * 128 + o] = f2bf(acc + Bias0[z * NOPEN + o]);
    } else if (v < 656) {
        prepw_piece(W, Wf1, Wf2, v - 512, 0, tid);
    } else if (v == 656) {
        if (tid == 0) sig[0] = 0.f;
        for (int idx = tid; idx < 1024; idx += 256) {
            int z = idx >> 9, rr = idx & 511;
            ushort* Zz = Zct + z * (1032 * 128);
            Zz[rr] = 0; Zz[1028 * 128 + rr] = 0;
        }
        for (int idx = tid; idx < 2048; idx += 256) {
            int a = idx >> 10, rr = idx & 1023;
            ushort* A = a ? At1 : At0;
            A[rr] = 0; A[1028 * 256 + rr] = 0;
        }
    } else {
        // v in [657, 721): zero A1 for layer 0's atomic accumulation
        int b = v - 657;
        size_t base = (size_t)b * 4096 + tid * 4;
        float4 z4 = {0.f, 0.f, 0.f, 0.f};
#pragma unroll
        for (int r = 0; r < 4; ++r) *(float4*)&A1[base + r * 1024] = z4;
    }
}

// ---------------- D2 = max(sq_i + sq_j - 2 Z^T Z, 0); sum(D2) -> sig ----------------
__global__ __launch_bounds__(256) void k_d2(const float* __restrict__ Zc,
                                            float* __restrict__ D2, float* __restrict__ sig) {
    __shared__ __align__(16) float Zi[32 * 36];
    __shared__ __align__(16) float Zj[32 * 68];
    __shared__ float sqi[32], sqj[64];
    __shared__ float red[4];
    const int tid = threadIdx.x;
    const int tx = tid & 15, ty = tid >> 4;
    const int j0 = blockIdx.x * 64, i0 = blockIdx.y * 32;
    if (tid < 32) sqi[tid] = 0.f;
    else if (tid < 96) sqj[tid - 32] = 0.f;
    float acc[2][4] = {};
    for (int c0 = 0; c0 < NOPEN; c0 += 32) {
        for (int idx = tid; idx < 32 * 32; idx += 256) {
            int c = idx >> 5, ii = idx & 31;
            Zi[c * 36 + ii] = Zc[(c0 + c) * NN + i0 + ii];
        }
        for (int idx = tid; idx < 32 * 64; idx += 256) {
            int c = idx >> 6, jj = idx & 63;
            Zj[c * 68 + jj] = Zc[(c0 + c) * NN + j0 + jj];
        }
        __syncthreads();
        if (tid < 32) {
            float s = 0.f;
            for (int c = 0; c < 32; ++c) { float x = Zi[c * 36 + tid]; s = fmaf(x, x, s); }
            sqi[tid] += s;
        } else if (tid < 96) {
            int jj = tid - 32;
            float s = 0.f;
            for (int c = 0; c < 32; ++c) { float x = Zj[c * 68 + jj]; s = fmaf(x, x, s); }
            sqj[jj] += s;
        }
#pragma unroll 8
        for (int c = 0; c < 32; ++c) {
            float2 zi = *(const float2*)&Zi[c * 36 + ty * 2];
            float4 zj = *(const float4*)&Zj[c * 68 + tx * 4];
            acc[0][0] = fmaf(zi.x, zj.x, acc[0][0]);
            acc[0][1] = fmaf(zi.x, zj.y, acc[0][1]);
            acc[0][2] = fmaf(zi.x, zj.z, acc[0][2]);
            acc[0][3] = fmaf(zi.x, zj.w, acc[0][3]);
            acc[1][0] = fmaf(zi.y, zj.x, acc[1][0]);
            acc[1][1] = fmaf(zi.y, zj.y, acc[1][1]);
            acc[1][2] = fmaf(zi.y, zj.z, acc[1][2]);
            acc[1][3] = fmaf(zi.y, zj.w, acc[1][3]);
        }
        __syncthreads();
    }
    float part = 0.f;
#pragma unroll
    for (int m = 0; m < 2; ++m) {
        int i = i0 + ty * 2 + m;
        float sqi_v = sqi[ty * 2 + m];
        float4 d;
        d.x = fmaxf(sqi_v + sqj[tx * 4 + 0] - 2.f * acc[m][0], 0.f);
        d.y = fmaxf(sqi_v + sqj[tx * 4 + 1] - 2.f * acc[m][1], 0.f);
        d.z = fmaxf(sqi_v + sqj[tx * 4 + 2] - 2.f * acc[m][2], 0.f);
        d.w = fmaxf(sqi_v + sqj[tx * 4 + 3] - 2.f * acc[m][3], 0.f);
        *(float4*)&D2[(size_t)i * NN + j0 + tx * 4] = d;
        part += (d.x + d.y) + (d.z + d.w);
    }
#pragma unroll
    for (int off = 32; off > 0; off >>= 1) part += __shfl_down(part, off);
    if ((tid & 63) == 0) red[tid >> 6] = part;
    __syncthreads();
    if (tid == 0) atomicAdd(sig, red[0] + red[1] + red[2] + red[3]);
}

// ---------------- deg_i = sum_j exp(-D2_ij/sigma); Dh_i = rsqrt(deg_i) ----------------
__global__ void k_deg(const float* __restrict__ D2, const float* __restrict__ sig,
                      float* __restrict__ Dh) {
    __shared__ float red[4];
    int i = blockIdx.x, tid = threadIdx.x;
    float inv = 1.f / (sig[0] * (1.f / 1048576.f) + 1e-12f);
    float4 v = *(const float4*)&D2[(size_t)i * NN + tid * 4];
    float s = __expf(-v.x * inv) + __expf(-v.y * inv) + __expf(-v.z * inv) + __expf(-v.w * inv);
#pragma unroll
    for (int off = 32; off > 0; off >>= 1) s += __shfl_down(s, off);
    if ((tid & 63) == 0) red[tid >> 6] = s;
    __syncthreads();
    if (tid == 0) Dh[i] = rsqrtf(red[0] + red[1] + red[2] + red[3]);
}

// ---------------- Lb_ij = bf16( delta_ij - Dh_i Dh_j exp(-D2_ij/sigma) ) ----------------
__global__ void k_L(const float* __restrict__ D2, const float* __restrict__ sig,
                    const float* __restrict__ Dh, ushort* __restrict__ Lb) {
    int i = blockIdx.x, tid = threadIdx.x;
    int j = tid * 4;
    float inv = 1.f / (sig[0] * (1.f / 1048576.f) + 1e-12f);
    float dhi = Dh[i];
    float4 v = *(const float4*)&D2[(size_t)i * NN + j];
    float4 dj = *(const float4*)&Dh[j];
    float4 o;
    o.x = -dhi * dj.x * __expf(-v.x * inv);
    o.y = -dhi * dj.y * __expf(-v.y * inv);
    o.z = -dhi * dj.z * __expf(-v.z * inv);
    o.w = -dhi * dj.w * __expf(-v.w * inv);
    if (i == j + 0) o.x += 1.f;
    if (i == j + 1) o.y += 1.f;
    if (i == j + 2) o.z += 1.f;
    if (i == j + 3) o.w += 1.f;
    ushort4 ob; ob.x = f2bf(o.x); ob.y = f2bf(o.y); ob.z = f2bf(o.z); ob.w = f2bf(o.w);
    *(ushort4*)&Lb[(size_t)i * NN + j] = ob;
}

// ---------------- MFMA conv1d + next-layer weight prep: grid 656 flattened ----------------
// b<512: conv (32 p-tiles of 32, 8 co, 2 z) reading Wf1 cur slot; b>=512: prepw into next slot.
// prepw rides here (hides under conv MFMA) instead of stretching the tiny leap dispatch.
__global__ __launch_bounds__(256) void k_convprep(const ushort* __restrict__ Zct,
        const ushort* __restrict__ Wf1, float* __restrict__ C0, ushort* __restrict__ C1b,
        const float* __restrict__ W, ushort* __restrict__ Wf1n, ushort* __restrict__ Wf2n,
        int lnext, int doprep) {
    const int b = blockIdx.x, tid = threadIdx.x;
    if (b >= 512) {
        if (doprep) prepw_piece(W, Wf1n, Wf2n, b - 512, lnext, tid);
        return;
    }
    const int xb = b & 31, yb = (b >> 5) & 7, z = b >> 8;
    const int p0 = xb * 32, co0 = yb * 32;
    __shared__ ushort Xs[40 * 136];
    const ushort* Zz = Zct + z * (1032 * 128);
    for (int idx = tid; idx < 640; idx += 256) {
        int row = idx >> 4, ch = (idx & 15) * 8;
        *(bfrag*)&Xs[row * 136 + ch] = *(const bfrag*)&Zz[(p0 + row) * 128 + ch];
    }
    __syncthreads();
    const int l = tid & 63, wv = tid >> 6;
    const int wm = wv >> 1, wn = wv & 1;
    const int lm = l & 15, lq = l >> 4;
    const ushort* wf = Wf1 + (((size_t)z * 144 + (yb * 2 + wm)) << 11) + l * 8;
    floatx4 acc = {};
    bfrag a_cur[4];
#pragma unroll
    for (int kc = 0; kc < 4; ++kc) a_cur[kc] = *(const bfrag*)(wf + (kc << 9));
    for (int t = 0; t < 9; ++t) {
        bfrag a_nxt[4];
        if (t < 8) {
            const ushort* wptr = wf + (size_t)(t + 1) * (16 << 11);
#pragma unroll
            for (int kc = 0; kc < 4; ++kc) a_nxt[kc] = *(const bfrag*)(wptr + (kc << 9));
        }
        const int xbase = (wn * 16 + lm + t) * 136 + lq * 8;
#pragma unroll
        for (int kc = 0; kc < 4; ++kc) {
            bfrag b0 = *(const bfrag*)&Xs[xbase + kc * 32];
            acc = __builtin_amdgcn_mfma_f32_16x16x32_bf16(a_cur[kc], b0, acc, 0, 0, 0);
        }
#pragma unroll
        for (int kc = 0; kc < 4; ++kc) a_cur[kc] = a_nxt[kc];
    }
    const int cog = co0 + wm * 16 + lq * 4;
    const int pg = p0 + wn * 16 + lm;
#pragma unroll
    for (int r = 0; r < 4; ++r) {
        if (z == 0) C0[(cog + r) * NN + pg] = acc[r];
        else        C1b[(cog + r) * NN + pg] = f2bf(acc[r]);
    }
}

// ---------------- MFMA split-K GEMM with atomic accumulate: Out += X[:,kc:]@L[kc:,:] ----------------
// grid (16 nt of 64, M/64 mt, 8 ksp); Out zeroed (A1) or pre-seeded (Tacc = convT z0) beforehand.
// Accumulation order nondeterministic but verified at the bf16 floor in R1+R5 binaries.
__global__ __launch_bounds__(256) void k_xl_mfma(const ushort* __restrict__ X,
                                                 const ushort* __restrict__ Lb,
                                                 float* __restrict__ Out) {
    __shared__ __align__(16) ushort As[64 * 136];
    __shared__ __align__(16) ushort Bs[64 * 136];
    const int tid = threadIdx.x;
    const int lane = tid & 63, wave = tid >> 6;
    const int wm = wave >> 1, wn = wave & 1;
    const int n0 = blockIdx.x * 64, m0 = blockIdx.y * 64, kc = blockIdx.z * 128;
    {
        int q = tid;
#pragma unroll
        for (int r = 0; r < 4; ++r, q += 256) {
            int row = q >> 4, ch = (q & 15) * 8;
            *(bfrag*)&As[row * 136 + ch] = *(const bfrag*)&X[(m0 + row) * NN + kc + ch];
        }
        q = tid;
#pragma unroll
        for (int r = 0; r < 4; ++r, q += 256) {
            int row = q >> 4, ch = (q & 15) * 8;
            *(bfrag*)&Bs[row * 136 + ch] = *(const bfrag*)&Lb[(n0 + row) * NN + kc + ch];
        }
    }
    __syncthreads();
    floatx4 acc[2][2] = {};
    const int lrow = (lane & 15) * 136;
    const int koff = (lane >> 4) * 8;
#pragma unroll
    for (int ks = 0; ks < 4; ++ks) {
        bfrag a[2], b[2];
#pragma unroll
        for (int i = 0; i < 2; ++i)
            a[i] = *(const bfrag*)&As[(wm * 32 + i * 16) * 136 + lrow + ks * 32 + koff];
#pragma unroll
        for (int j = 0; j < 2; ++j)
            b[j] = *(const bfrag*)&Bs[(wn * 32 + j * 16) * 136 + lrow + ks * 32 + koff];
#pragma unroll
        for (int i = 0; i < 2; ++i)
#pragma unroll
            for (int j = 0; j < 2; ++j)
                acc[i][j] = __builtin_amdgcn_mfma_f32_16x16x32_bf16(a[i], b[j], acc[i][j], 0, 0, 0);
    }
    const int mg0 = m0 + wm * 32 + (lane >> 4) * 4;
    const int ng0 = n0 + wn * 32 + (lane & 15);
#pragma unroll
    for (int i = 0; i < 2; ++i)
#pragma unroll
        for (int j = 0; j < 2; ++j)
#pragma unroll
            for (int r = 0; r < 4; ++r)
                atomicAdd(&Out[(size_t)(mg0 + i * 16 + r) * NN + ng0 + j * 16], acc[i][j][r]);
}

// ---------------- instance norm stats over C0 (arr=0) / A1 (arr=1) ----------------
// grid (NHID, 2), one channel per block
__global__ void k_inorm(const float* __restrict__ C0, const float* __restrict__ A1,
                        float* __restrict__ Mu, float* __restrict__ Rs) {
    const int c = blockIdx.x, arr = blockIdx.y, tid = threadIdx.x;
    __shared__ float rs[4], rq[4];
    const float* in = arr ? A1 : C0;
    float4 v = *(const float4*)&in[c * NN + tid * 4];
    float s = (v.x + v.y) + (v.z + v.w);
    float q = (v.x * v.x + v.y * v.y) + (v.z * v.z + v.w * v.w);
#pragma unroll
    for (int off = 32; off > 0; off >>= 1) { s += __shfl_down(s, off); q += __shfl_down(q, off); }
    if ((tid & 63) == 0) { rs[tid >> 6] = s; rq[tid >> 6] = q; }
    __syncthreads();
    if (tid == 0) {
        float S = rs[0] + rs[1] + rs[2] + rs[3];
        float Q = rq[0] + rq[1] + rq[2] + rq[3];
        float mean = S * (1.f / NN);
        float var = Q * (1.f / NN) - mean * mean;
        Mu[arr * NHID + c] = mean;
        Rs[arr * NHID + c] = rsqrtf(var + IN_EPS);
    }
}

// ---------------- normalize + relu + bf16 + transpose -> At[pos+4][co] ----------------
// grid (32 p, 4 co64, 2 arr)
__global__ __launch_bounds__(256) void k_normT(const float* __restrict__ C0,
        const float* __restrict__ A1, const float* __restrict__ Mu, const float* __restrict__ Rs,
        ushort* __restrict__ At0, ushort* __restrict__ At1) {
    const int arr = blockIdx.z;
    const int p0 = blockIdx.x * 32, co0 = blockIdx.y * 64;
    const float* in = arr ? A1 : C0;
    ushort* out = arr ? At1 : At0;
    __shared__ ushort Ls[32 * 72];
    const int tid = threadIdx.x;
#pragma unroll
    for (int r = 0; r < 2; ++r) {
        int idx = r * 256 + tid;      // 64 co x 8 p-chunks(4)
        int col = idx >> 3, pq = idx & 7;
        int co = co0 + col;
        float4 v = *(const float4*)&in[(size_t)co * NN + p0 + pq * 4];
        float m = Mu[arr * NHID + co], sc = Rs[arr * NHID + co];
        Ls[(pq * 4 + 0) * 72 + col] = f2bf(fmaxf((v.x - m) * sc, 0.f));
        Ls[(pq * 4 + 1) * 72 + col] = f2bf(fmaxf((v.y - m) * sc, 0.f));
        Ls[(pq * 4 + 2) * 72 + col] = f2bf(fmaxf((v.z - m) * sc, 0.f));
        Ls[(pq * 4 + 3) * 72 + col] = f2bf(fmaxf((v.w - m) * sc, 0.f));
    }
    __syncthreads();
    {
        int row = tid >> 3, ch = (tid & 7) * 8;   // 32 rows x 8 chunks(8)
        *(bfrag*)&out[(size_t)(p0 + row + 4) * 256 + co0 + ch] = *(const bfrag*)&Ls[row * 72 + ch];
    }
}

// ---------------- MFMA convT + A1/sig zero: grid 577 flattened ----------------
// b<512: convT (32 p, 8 ci16, 2 z); b in [512,576): zero A1 (normT already consumed it); b==576: sig=0
__global__ __launch_bounds__(256) void k_convT_misc(const ushort* __restrict__ At0,
        const ushort* __restrict__ At1, const ushort* __restrict__ Wf2,
        float* __restrict__ Tacc, ushort* __restrict__ T1b,
        float* __restrict__ A1, float* __restrict__ sig) {
    const int b = blockIdx.x, tid = threadIdx.x;
    if (b >= 512) {
        if (b == 576) {
            if (tid == 0) sig[0] = 0.f;
        } else {
            int piece = b - 512;
            size_t base = (size_t)piece * 4096 + tid * 4;
            float4 z4 = {0.f, 0.f, 0.f, 0.f};
#pragma unroll
            for (int r = 0; r < 4; ++r) *(float4*)&A1[base + r * 1024] = z4;
        }
        return;
    }
    const int xb = b & 31, yb = (b >> 5) & 7, z = b >> 8;
    const int p0 = xb * 32, ci0 = yb * 16;
    __shared__ ushort Al[40 * 264];
    __shared__ float Red[2][64][4];
    const ushort* A = z ? At1 : At0;
    for (int idx = tid; idx < 1280; idx += 256) {
        int row = idx >> 5, ch = (idx & 31) * 8;
        *(bfrag*)&Al[row * 264 + ch] = *(const bfrag*)&A[(p0 + row) * 256 + ch];
    }
    __syncthreads();
    const int l = tid & 63, wv = tid >> 6;
    const int ph = wv & 1, kh = wv >> 1;   // p-half, k-half
    const int lm = l & 15, lq = l >> 4;
    const ushort* wbase = Wf2 + (((size_t)z * 72 + yb) << 12) + ((kh * 4) << 9) + l * 8;
    floatx4 acc0 = {}, acc1 = {};
    bfrag a_cur[4];
#pragma unroll
    for (int jj = 0; jj < 4; ++jj) a_cur[jj] = *(const bfrag*)(wbase + (jj << 9));
    for (int t = 0; t < 9; ++t) {
        bfrag a_nxt[4];
        if (t < 8) {
            const ushort* wptr = wbase + (size_t)(t + 1) * (8 << 12);
#pragma unroll
            for (int jj = 0; jj < 4; ++jj) a_nxt[jj] = *(const bfrag*)(wptr + (jj << 9));
        }
        const int abase = (ph * 16 + lm + 8 - t) * 264 + lq * 8;
#pragma unroll
        for (int jj = 0; jj < 4; jj += 2) {
            bfrag b0 = *(const bfrag*)&Al[abase + (kh * 4 + jj) * 32];
            acc0 = __builtin_amdgcn_mfma_f32_16x16x32_bf16(a_cur[jj], b0, acc0, 0, 0, 0);
            bfrag b1 = *(const bfrag*)&Al[abase + (kh * 4 + jj + 1) * 32];
            acc1 = __builtin_amdgcn_mfma_f32_16x16x32_bf16(a_cur[jj + 1], b1, acc1, 0, 0, 0);
        }
#pragma unroll
        for (int jj = 0; jj < 4; ++jj) a_cur[jj] = a_nxt[jj];
    }
    floatx4 acc = acc0 + acc1;
    __syncthreads();
    if (kh == 1) {
#pragma unroll
        for (int r = 0; r < 4; ++r) Red[ph][l][r] = acc[r];
    }
    __syncthreads();
    if (kh == 0) {
#pragma unroll
        for (int r = 0; r < 4; ++r) acc[r] += Red[ph][l][r];
        const int cig = ci0 + lq * 4;
        const int pg = p0 + ph * 16 + lm;
#pragma unroll
        for (int r = 0; r < 4; ++r) {
            if (z == 0) Tacc[(cig + r) * NN + pg] = acc[r];
            else        T1b[(cig + r) * NN + pg] = f2bf(acc[r]);
        }
    }
}

// ---------------- leapfrog tail: grid 128, pure (prepw/zeros moved to earlier dispatches) ----------------
__global__ __launch_bounds__(256) void k_leap(const float* __restrict__ Tacc,
        const float* __restrict__ Zc, float* __restrict__ Zo,
        const float* __restrict__ BiasN, ushort* __restrict__ Zct) {
    const int v = blockIdx.x, tid = threadIdx.x;
    int off = (v * 256 + tid) * 4;
    float4 a = *(const float4*)&Tacc[off];
    float4 zc = *(const float4*)&Zc[off];
    float4 zo = *(const float4*)&Zo[off];
    float4 zn;
    zn.x = 2.f * zc.x - zo.x - H2 * a.x;
    zn.y = 2.f * zc.y - zo.y - H2 * a.y;
    zn.z = 2.f * zc.z - zo.z - H2 * a.z;
    zn.w = 2.f * zc.w - zo.w - H2 * a.w;
    *(float4*)&Zo[off] = zn;
    int ci = off >> 10, n = off & 1023;
#pragma unroll
    for (int z = 0; z < 2; ++z) {
        float bz = BiasN[z * NOPEN + ci];
        ushort* Zz = Zct + z * (1032 * 128);
        Zz[(n + 4) * 128 + ci] = f2bf(zn.x + bz);
        Zz[(n + 5) * 128 + ci] = f2bf(zn.y + bz);
        Zz[(n + 6) * 128 + ci] = f2bf(zn.z + bz);
        Zz[(n + 7) * 128 + ci] = f2bf(zn.w + bz);
    }
}

// ---------------- closing: out = concat(Kclose @ Zc, Kclose @ Zold) ----------------
__global__ void k_close(const float* __restrict__ Kclose, const float* __restrict__ Zc,
                        const float* __restrict__ Zold, float* __restrict__ out) {
    int n = blockIdx.x * 256 + threadIdx.x;
    int o = blockIdx.y;
    const float* Zb = blockIdx.z ? Zold : Zc;
    float a = 0.f;
#pragma unroll
    for (int c = 0; c < NOPEN; ++c) a = fmaf(Kclose[o * NOPEN + c], Zb[c * NN + n], a);
    out[blockIdx.z * (NCLOSE * NN) + o * NN + n] = a;
}

extern "C" void kernel_launch(void* const* d_in, const int* in_sizes, int n_in,
                              void* d_out, int out_size, void* d_ws, size_t ws_size,
                              hipStream_t stream) {
    const float* Z      = (const float*)d_in[0];
    const float* Kopen  = (const float*)d_in[1];
    const float* Kclose = (const float*)d_in[2];
    const float* W      = (const float*)d_in[3];
    const float* Bias   = (const float*)d_in[4];
    float* out = (float*)d_out;
    float* ws  = (float*)d_ws;

    // workspace layout (float units)
    float* Zb0   = ws + 0;         // 131072
    float* Zb1   = ws + 131072;    // 131072
    float* D2    = ws + 262144;    // 1048576
    float* C0    = ws + 1310720;   // 262144
    float* A1    = ws + 1572864;   // 262144
    float* Tacc  = ws + 1835008;   // 131072
    float* Dh    = ws + 5111808;   // 1024
    float* sig   = ws + 5112832;   // 1024
    float* Mu    = ws + 5113856;   // 1024 (512 used)
    float* Rs    = ws + 5114880;   // 1024
    ushort* Lb  = (ushort*)(ws + 5115904); // 1024*1024 us
    ushort* C1b = (ushort*)(ws + 5640192); // 256*1024 us
    ushort* T1b = (ushort*)(ws + 5771264); // 128*1024 us
    ushort* Zct = (ushort*)(ws + 5836800); // 2*1032*128 us
    ushort* At0 = (ushort*)(ws + 5968896); // 1032*256 us
    ushort* At1 = (ushort*)(ws + 6100992); // 1032*256 us
    ushort* Wf1a = (ushort*)(ws + 6233088); // 294912 us (conv frags, slot 0)
    ushort* Wf2a = (ushort*)(ws + 6380544); // 294912 us (convT frags, slot 0)
    ushort* Wf1b = (ushort*)(ws + 6528000); // 294912 us (slot 1)
    ushort* Wf2b = (ushort*)(ws + 6675456); // 294912 us (slot 1), ends 6822912

    ushort* Wf1s[2] = { Wf1a, Wf1b };
    ushort* Wf2s[2] = { Wf2a, Wf2b };

    k_open<<<dim3(721), 256, 0, stream>>>(Kopen, Z, Zb0, Zb1, Bias, Zct, At0, At1,
                                          W, Wf1s[0], Wf2s[0], sig, A1);

    float* Zc = Zb0;
    float* Zold = Zb1;
    for (int i = 0; i < NLAYERS; ++i) {
        const int cur = i & 1, nxt = cur ^ 1;
        const int lnext = (i + 1 < NLAYERS) ? i + 1 : NLAYERS - 1;
        const int doprep = (i + 1 < NLAYERS) ? 1 : 0;
        if (i % 10 == 0) {
            k_d2<<<dim3(16, 32), 256, 0, stream>>>(Zc, D2, sig);
            k_deg<<<dim3(NN), 256, 0, stream>>>(D2, sig, Dh);
            k_L<<<dim3(NN), 256, 0, stream>>>(D2, sig, Dh, Lb);
        }
        k_convprep<<<dim3(656), 256, 0, stream>>>(Zct, Wf1s[cur], C0, C1b,
                                                  W, Wf1s[nxt], Wf2s[nxt], lnext, doprep);
        k_xl_mfma<<<dim3(16, 4, 8), 256, 0, stream>>>(C1b, Lb, A1);    // XL1 -> A1 (zeroed)
        k_inorm<<<dim3(NHID, 2), 256, 0, stream>>>(C0, A1, Mu, Rs);
        k_normT<<<dim3(32, 4, 2), 256, 0, stream>>>(C0, A1, Mu, Rs, At0, At1);
        k_convT_misc<<<dim3(577), 256, 0, stream>>>(At0, At1, Wf2s[cur], Tacc, T1b, A1, sig);
        k_xl_mfma<<<dim3(16, 2, 8), 256, 0, stream>>>(T1b, Lb, Tacc);  // XL2 += into Tacc
        k_leap<<<dim3(128), 256, 0, stream>>>(Tacc, Zc, Zold,
                                              Bias + (size_t)lnext * 2 * NOPEN, Zct);
        float* tmp = Zc; Zc = Zold; Zold = tmp;
    }

    k_close<<<dim3(4, NCLOSE, 2), 256, 0, stream>>>(Kclose, Zc, Zold, out);
}